// Round 2
// baseline (593.292 us; speedup 1.0000x reference)
//
#include <hip/hip_runtime.h>
#include <hip/hip_bf16.h>

#define N_NODES 50000
#define N_EDGES 800000
#define IN_DIM  256
#define HID     128
#define LEAKY   0.01f

#define EDGE_BLOCKS  ((N_EDGES + 255) / 256)      // 3125
#define NODE_WBLKS   (N_NODES / 4)                // 12500 (4 waves/block, exact)
#define SCAN_BLOCKS  ((N_NODES + 255) / 256)      // 196
#define GEMM_WAVES   (N_NODES / 16)               // 3125
#define GEMM_BLOCKS  ((GEMM_WAVES + 3) / 4)       // 782

typedef __attribute__((ext_vector_type(8))) short short8;
typedef __attribute__((ext_vector_type(4))) float f32x4;

__device__ __forceinline__ unsigned short f2bf(float x) {
    union { __hip_bfloat16 b; unsigned short u; } c;
    c.b = __float2bfloat16(x);
    return c.u;
}
__device__ __forceinline__ float bf2f(unsigned short u) {
    union { unsigned int u; float f; } c;
    c.u = ((unsigned int)u) << 16;
    return c.f;
}

// ---------------- CSR build (dst identical for both layers) ----------------

__global__ void hist_kernel(const int* __restrict__ dst, int* __restrict__ counts) {
    int i = blockIdx.x * 256 + threadIdx.x;
    if (i < N_EDGES) atomicAdd(&counts[dst[i]], 1);
}

__global__ void scan_block(const int* __restrict__ counts, int* __restrict__ offsets,
                           int* __restrict__ bsums) {
    __shared__ int sh[256];
    int tid = threadIdx.x;
    int i = blockIdx.x * 256 + tid;
    int v = (i < N_NODES) ? counts[i] : 0;
    sh[tid] = v;
    __syncthreads();
    for (int o = 1; o < 256; o <<= 1) {
        int t = (tid >= o) ? sh[tid - o] : 0;
        __syncthreads();
        sh[tid] += t;
        __syncthreads();
    }
    if (i < N_NODES) offsets[i] = sh[tid] - v;   // exclusive within block
    if (tid == 255) bsums[blockIdx.x] = sh[255];
}

__global__ void scan_tops(const int* __restrict__ bsums, int* __restrict__ boffs) {
    __shared__ int sh[256];
    int tid = threadIdx.x;
    int v = (tid < SCAN_BLOCKS) ? bsums[tid] : 0;
    sh[tid] = v;
    __syncthreads();
    for (int o = 1; o < 256; o <<= 1) {
        int t = (tid >= o) ? sh[tid - o] : 0;
        __syncthreads();
        sh[tid] += t;
        __syncthreads();
    }
    if (tid < SCAN_BLOCKS) boffs[tid] = sh[tid] - v;
}

__global__ void scan_add(int* __restrict__ offsets, const int* __restrict__ boffs) {
    int i = blockIdx.x * 256 + threadIdx.x;
    if (i < N_NODES) offsets[i] += boffs[blockIdx.x];
}

__global__ void fill_kernel(const int* __restrict__ dst, const int* __restrict__ offsets,
                            int* __restrict__ cursor, int* __restrict__ perm) {
    int i = blockIdx.x * 256 + threadIdx.x;
    if (i < N_EDGES) {
        int d = dst[i];
        int p = atomicAdd(&cursor[d], 1);
        perm[offsets[d] + p] = i;
    }
}

// ---------------- W split into bf16 hi/lo planes ----------------

__global__ void split_w(const float* __restrict__ W, unsigned short* __restrict__ hi,
                        unsigned short* __restrict__ lo, int n) {
    int i = blockIdx.x * 256 + threadIdx.x;
    if (i < n) {
        float x = W[i];
        unsigned short h = f2bf(x);
        hi[i] = h;
        lo[i] = f2bf(x - bf2f(h));
    }
}

// ---------------- FC1: Z[m][n] = sum_k A[m][k] W[n][k] + b[n], A fp32 ----------------
// split-precision: A and W in hi+lo bf16, acc += Ah*Bh + Al*Bh + Ah*Bl (fp32-accurate)

__launch_bounds__(256)
__global__ void gemm_fc1(const float* __restrict__ A,
                         const unsigned short* __restrict__ Whi,
                         const unsigned short* __restrict__ Wlo,
                         const float* __restrict__ bias,
                         float* __restrict__ Z) {
    int wave = blockIdx.x * 4 + (threadIdx.x >> 6);
    if (wave >= GEMM_WAVES) return;
    int lane = threadIdx.x & 63;
    int m0 = wave * 16;
    int r  = lane & 15;
    int ko = (lane >> 4) * 8;

    const float* Ap = A + (size_t)(m0 + r) * IN_DIM + ko;
    const unsigned short* Wh = Whi + (size_t)r * IN_DIM + ko;
    const unsigned short* Wl = Wlo + (size_t)r * IN_DIM + ko;

    f32x4 acc[8];
#pragma unroll
    for (int i = 0; i < 8; i++) acc[i] = (f32x4){0.f, 0.f, 0.f, 0.f};

#pragma unroll
    for (int kt = 0; kt < IN_DIM / 32; kt++) {
        float4 f0 = *(const float4*)(Ap + kt * 32);
        float4 f1 = *(const float4*)(Ap + kt * 32 + 4);
        float xs[8] = {f0.x, f0.y, f0.z, f0.w, f1.x, f1.y, f1.z, f1.w};
        short8 ahi, alo;
#pragma unroll
        for (int j = 0; j < 8; j++) {
            unsigned short hbits = f2bf(xs[j]);
            ahi[j] = (short)hbits;
            alo[j] = (short)f2bf(xs[j] - bf2f(hbits));
        }
#pragma unroll
        for (int nt = 0; nt < 8; nt++) {
            short8 bhi = *(const short8*)(Wh + (size_t)nt * 16 * IN_DIM + kt * 32);
            short8 blo = *(const short8*)(Wl + (size_t)nt * 16 * IN_DIM + kt * 32);
            acc[nt] = __builtin_amdgcn_mfma_f32_16x16x32_bf16(ahi, bhi, acc[nt], 0, 0, 0);
            acc[nt] = __builtin_amdgcn_mfma_f32_16x16x32_bf16(alo, bhi, acc[nt], 0, 0, 0);
            acc[nt] = __builtin_amdgcn_mfma_f32_16x16x32_bf16(ahi, blo, acc[nt], 0, 0, 0);
        }
    }

    // C/D layout: col = lane&15, row = (lane>>4)*4 + reg  [m89-verified]
    int rowbase = m0 + (lane >> 4) * 4;
#pragma unroll
    for (int nt = 0; nt < 8; nt++) {
        int n = nt * 16 + r;
        float bn = bias[n];
#pragma unroll
        for (int reg = 0; reg < 4; reg++) {
            Z[(size_t)(rowbase + reg) * HID + n] = acc[nt][reg] + bn;
        }
    }
}

// ---------------- FC2: A is h1 (single bf16 plane), W split hi/lo ----------------

__launch_bounds__(256)
__global__ void gemm_fc2(const unsigned short* __restrict__ Abf,
                         const unsigned short* __restrict__ Whi,
                         const unsigned short* __restrict__ Wlo,
                         const float* __restrict__ bias,
                         float* __restrict__ Z) {
    int wave = blockIdx.x * 4 + (threadIdx.x >> 6);
    if (wave >= GEMM_WAVES) return;
    int lane = threadIdx.x & 63;
    int m0 = wave * 16;
    int r  = lane & 15;
    int ko = (lane >> 4) * 8;

    const unsigned short* Ap = Abf + (size_t)(m0 + r) * HID + ko;
    const unsigned short* Wh = Whi + (size_t)r * HID + ko;
    const unsigned short* Wl = Wlo + (size_t)r * HID + ko;

    f32x4 acc[8];
#pragma unroll
    for (int i = 0; i < 8; i++) acc[i] = (f32x4){0.f, 0.f, 0.f, 0.f};

#pragma unroll
    for (int kt = 0; kt < HID / 32; kt++) {
        short8 af = *(const short8*)(Ap + kt * 32);
#pragma unroll
        for (int nt = 0; nt < 8; nt++) {
            short8 bhi = *(const short8*)(Wh + (size_t)nt * 16 * HID + kt * 32);
            short8 blo = *(const short8*)(Wl + (size_t)nt * 16 * HID + kt * 32);
            acc[nt] = __builtin_amdgcn_mfma_f32_16x16x32_bf16(af, bhi, acc[nt], 0, 0, 0);
            acc[nt] = __builtin_amdgcn_mfma_f32_16x16x32_bf16(af, blo, acc[nt], 0, 0, 0);
        }
    }

    int rowbase = m0 + (lane >> 4) * 4;
#pragma unroll
    for (int nt = 0; nt < 8; nt++) {
        int n = nt * 16 + r;
        float bn = bias[n];
#pragma unroll
        for (int reg = 0; reg < 4; reg++) {
            Z[(size_t)(rowbase + reg) * HID + n] = acc[nt][reg] + bn;
        }
    }
}

// ---------------- per-node attention partial scores (a is fp32) ----------------

__launch_bounds__(256)
__global__ void node_scores(const float* __restrict__ Z,
                            const float* __restrict__ a,
                            float* __restrict__ sS, float* __restrict__ sD) {
    int node = blockIdx.x * 4 + (threadIdx.x >> 6);
    int lane = threadIdx.x & 63;
    float2 z = *(const float2*)(Z + (size_t)node * HID + lane * 2);
    float ps = z.x * a[2 * lane]       + z.y * a[2 * lane + 1];
    float pd = z.x * a[HID + 2 * lane] + z.y * a[HID + 2 * lane + 1];
#pragma unroll
    for (int o = 32; o > 0; o >>= 1) {
        ps += __shfl_xor(ps, o, 64);
        pd += __shfl_xor(pd, o, 64);
    }
    if (lane == 0) { sS[node] = ps; sD[node] = pd; }
}

// ---------------- segment softmax + weighted gather-sum + ELU ----------------
// one wave per dst node. OUT_PLANES=1: write bf16 h1 plane; 0: write fp32 out.

template <int OUT_PLANES>
__launch_bounds__(256)
__global__ void aggregate(const float* __restrict__ Z,
                          const int* __restrict__ src,
                          const int* __restrict__ perm,
                          const int* __restrict__ offsets,
                          const int* __restrict__ counts,
                          const float* __restrict__ sS,
                          const float* __restrict__ sD,
                          const float* __restrict__ ab,
                          unsigned short* __restrict__ OutBf,
                          float* __restrict__ OutF) {
    int v = blockIdx.x * 4 + (threadIdx.x >> 6);
    int lane = threadIdx.x & 63;
    int off = offsets[v];
    int deg = counts[v];
    float sdv = sD[v] + ab[0];

    // phase A: segment max of leaky_relu(e)
    float mx = -3.0e38f;
    for (int t = lane; t < deg; t += 64) {
        int e = perm[off + t];
        float x = sS[src[e]] + sdv;
        x = x > 0.f ? x : LEAKY * x;
        mx = fmaxf(mx, x);
    }
#pragma unroll
    for (int o = 32; o > 0; o >>= 1) mx = fmaxf(mx, __shfl_xor(mx, o, 64));

    // phase B: softmax denom
    float sum = 0.f;
    for (int t = lane; t < deg; t += 64) {
        int e = perm[off + t];
        float x = sS[src[e]] + sdv;
        x = x > 0.f ? x : LEAKY * x;
        sum += __expf(x - mx);
    }
#pragma unroll
    for (int o = 32; o > 0; o >>= 1) sum += __shfl_xor(sum, o, 64);
    float inv = (deg > 0) ? 1.f / sum : 0.f;

    // phase C: weighted sum of z[src] rows (lane covers dims 2*lane, 2*lane+1)
    float2 acc = {0.f, 0.f};
    for (int t = 0; t < deg; t++) {
        int e = perm[off + t];
        int s = src[e];
        float x = sS[s] + sdv;
        x = x > 0.f ? x : LEAKY * x;
        float alpha = __expf(x - mx) * inv;
        float2 zz = *(const float2*)(Z + (size_t)s * HID + lane * 2);
        acc.x += alpha * zz.x;
        acc.y += alpha * zz.y;
    }

    // ELU
    acc.x = acc.x > 0.f ? acc.x : __expf(acc.x) - 1.f;
    acc.y = acc.y > 0.f ? acc.y : __expf(acc.y) - 1.f;

    if (OUT_PLANES) {
        ushort2 o2;
        o2.x = f2bf(acc.x);
        o2.y = f2bf(acc.y);
        *((ushort2*)(OutBf + (size_t)v * HID + lane * 2)) = o2;
    } else {
        float2 o2 = {acc.x, acc.y};
        *((float2*)(OutF + (size_t)v * HID + lane * 2)) = o2;
    }
}

// ---------------- launch ----------------

extern "C" void kernel_launch(void* const* d_in, const int* in_sizes, int n_in,
                              void* d_out, int out_size, void* d_ws, size_t ws_size,
                              hipStream_t stream) {
    const float* h   = (const float*)d_in[0];
    const int*   src = (const int*)d_in[1];
    const int*   dst = (const int*)d_in[2];
    const float* W1  = (const float*)d_in[3];
    const float* b1  = (const float*)d_in[4];
    const float* a1  = (const float*)d_in[5];
    const float* ab1 = (const float*)d_in[6];
    const float* W2  = (const float*)d_in[7];
    const float* b2  = (const float*)d_in[8];
    const float* a2  = (const float*)d_in[9];
    const float* ab2 = (const float*)d_in[10];
    float* out = (float*)d_out;

    // workspace carve-up (all offsets 16B-aligned)
    float* z  = (float*)d_ws;                              // 50000*128 f32 = 25.6 MB
    float* sS = z + (size_t)N_NODES * HID;                 // 50000 f32
    float* sD = sS + N_NODES;                              // 50000 f32
    unsigned short* h1   = (unsigned short*)(sD + N_NODES);      // 50000*128 bf16
    unsigned short* w1hi = h1 + (size_t)N_NODES * HID;           // 128*256
    unsigned short* w1lo = w1hi + HID * IN_DIM;
    unsigned short* w2hi = w1lo + HID * IN_DIM;                  // 128*128
    unsigned short* w2lo = w2hi + HID * HID;
    int* counts  = (int*)(w2lo + HID * HID);
    int* offsets = counts + N_NODES;
    int* cursor  = offsets + N_NODES;
    int* bsums   = cursor + N_NODES;
    int* boffs   = bsums + 256;
    int* perm    = boffs + 256;                            // 800000 i32

    hipMemsetAsync(counts, 0, N_NODES * sizeof(int), stream);
    hipMemsetAsync(cursor, 0, N_NODES * sizeof(int), stream);

    // CSR by dst (shared by both layers)
    hist_kernel<<<EDGE_BLOCKS, 256, 0, stream>>>(dst, counts);
    scan_block<<<SCAN_BLOCKS, 256, 0, stream>>>(counts, offsets, bsums);
    scan_tops<<<1, 256, 0, stream>>>(bsums, boffs);
    scan_add<<<SCAN_BLOCKS, 256, 0, stream>>>(offsets, boffs);
    fill_kernel<<<EDGE_BLOCKS, 256, 0, stream>>>(dst, offsets, cursor, perm);

    // weight splits
    split_w<<<(HID * IN_DIM + 255) / 256, 256, 0, stream>>>(W1, w1hi, w1lo, HID * IN_DIM);
    split_w<<<(HID * HID + 255) / 256, 256, 0, stream>>>(W2, w2hi, w2lo, HID * HID);

    // layer 1
    gemm_fc1<<<GEMM_BLOCKS, 256, 0, stream>>>(h, w1hi, w1lo, b1, z);
    node_scores<<<NODE_WBLKS, 256, 0, stream>>>(z, a1, sS, sD);
    aggregate<1><<<NODE_WBLKS, 256, 0, stream>>>(z, src, perm, offsets, counts, sS, sD, ab1, h1, nullptr);

    // layer 2
    gemm_fc2<<<GEMM_BLOCKS, 256, 0, stream>>>(h1, w2hi, w2lo, b2, z);
    node_scores<<<NODE_WBLKS, 256, 0, stream>>>(z, a2, sS, sD);
    aggregate<0><<<NODE_WBLKS, 256, 0, stream>>>(z, src, perm, offsets, counts, sS, sD, ab2, nullptr, out);
}

// Round 3
// 393.000 us; speedup vs baseline: 1.5096x; 1.5096x over previous
//
#include <hip/hip_runtime.h>
#include <hip/hip_bf16.h>

#define N_NODES 50000
#define N_EDGES 800000
#define IN_DIM  256
#define HID     128
#define LEAKY   0.01f

#define EDGE_BLOCKS  ((N_EDGES + 255) / 256)      // 3125
#define NODE_WBLKS   (N_NODES / 4)                // 12500 (4 waves/block, exact)
#define SCAN_BLOCKS  ((N_NODES + 255) / 256)      // 196 (also covers N_NODES+1 slot)
#define GEMM_WAVES   (N_NODES / 16)               // 3125
#define GEMM_BLOCKS  ((GEMM_WAVES + 3) / 4)       // 782

typedef __attribute__((ext_vector_type(8))) short short8;
typedef __attribute__((ext_vector_type(4))) float f32x4;

__device__ __forceinline__ unsigned short f2bf(float x) {
    union { __hip_bfloat16 b; unsigned short u; } c;
    c.b = __float2bfloat16(x);
    return c.u;
}
__device__ __forceinline__ float bf2f(unsigned short u) {
    union { unsigned int u; float f; } c;
    c.u = ((unsigned int)u) << 16;
    return c.f;
}
__device__ __forceinline__ float2 bfu2(unsigned int u) {
    float2 r;
    r.x = bf2f((unsigned short)(u & 0xffff));
    r.y = bf2f((unsigned short)(u >> 16));
    return r;
}
__device__ __forceinline__ float lky(float x) { return x > 0.f ? x : LEAKY * x; }

// ---------------- CSR build (dst identical for both layers) ----------------

__global__ void hist_kernel(const int* __restrict__ dst, int* __restrict__ counts) {
    int i = blockIdx.x * 256 + threadIdx.x;
    if (i < N_EDGES) atomicAdd(&counts[dst[i]], 1);
}

__global__ void scan_block(const int* __restrict__ counts, int* __restrict__ offsets,
                           int* __restrict__ bsums) {
    __shared__ int sh[256];
    int tid = threadIdx.x;
    int i = blockIdx.x * 256 + tid;
    int v = (i < N_NODES) ? counts[i] : 0;
    sh[tid] = v;
    __syncthreads();
    for (int o = 1; o < 256; o <<= 1) {
        int t = (tid >= o) ? sh[tid - o] : 0;
        __syncthreads();
        sh[tid] += t;
        __syncthreads();
    }
    if (i < N_NODES) offsets[i] = sh[tid] - v;   // exclusive within block
    if (tid == 255) bsums[blockIdx.x] = sh[255];
}

__global__ void scan_tops(const int* __restrict__ bsums, int* __restrict__ boffs) {
    __shared__ int sh[256];
    int tid = threadIdx.x;
    int v = (tid < SCAN_BLOCKS) ? bsums[tid] : 0;
    sh[tid] = v;
    __syncthreads();
    for (int o = 1; o < 256; o <<= 1) {
        int t = (tid >= o) ? sh[tid - o] : 0;
        __syncthreads();
        sh[tid] += t;
        __syncthreads();
    }
    if (tid < SCAN_BLOCKS) boffs[tid] = sh[tid] - v;
}

__global__ void scan_add(int* __restrict__ offsets, const int* __restrict__ boffs) {
    int i = blockIdx.x * 256 + threadIdx.x;
    if (i < N_NODES) offsets[i] += boffs[blockIdx.x];
    if (i == N_NODES) offsets[N_NODES] = N_EDGES;
}

// fill: csr_src[slot] = src[edge]  (removes one indirection level from aggregate)
__global__ void fill_kernel(const int* __restrict__ dst, const int* __restrict__ src,
                            const int* __restrict__ offsets,
                            int* __restrict__ cursor, int* __restrict__ csr_src) {
    int i = blockIdx.x * 256 + threadIdx.x;
    if (i < N_EDGES) {
        int d = dst[i];
        int p = atomicAdd(&cursor[d], 1);
        csr_src[offsets[d] + p] = src[i];
    }
}

// ---------------- W split into bf16 hi/lo planes ----------------

__global__ void split_w(const float* __restrict__ W, unsigned short* __restrict__ hi,
                        unsigned short* __restrict__ lo, int n) {
    int i = blockIdx.x * 256 + threadIdx.x;
    if (i < n) {
        float x = W[i];
        unsigned short h = f2bf(x);
        hi[i] = h;
        lo[i] = f2bf(x - bf2f(h));
    }
}

// ---------------- GEMM epilogue: bias + bf16 z store + fused attention scores ----
// C/D layout: col = lane&15, row = (lane>>4)*4 + reg  [m89-verified].
// Lanes sharing (lane>>4) hold the same 4 rows, partition cols by r=lane&15:
// shfl_xor over r gives the full row dot with a[:HID] / a[HID:].

__device__ __forceinline__ void gemm_epilogue(
        f32x4* acc, int m0, int lane,
        const float* __restrict__ bias, const float* __restrict__ attn,
        unsigned short* __restrict__ Zb, float* __restrict__ sS, float* __restrict__ sD) {
    int r = lane & 15;
    int rowbase = m0 + (lane >> 4) * 4;
    float ps[4] = {0.f, 0.f, 0.f, 0.f};
    float pd[4] = {0.f, 0.f, 0.f, 0.f};
#pragma unroll
    for (int nt = 0; nt < 8; nt++) {
        int n = nt * 16 + r;
        float bn = bias[n];
        float aS = attn[n];
        float aD = attn[HID + n];
#pragma unroll
        for (int reg = 0; reg < 4; reg++) {
            float zv = acc[nt][reg] + bn;
            Zb[(size_t)(rowbase + reg) * HID + n] = f2bf(zv);
            ps[reg] += zv * aS;
            pd[reg] += zv * aD;
        }
    }
#pragma unroll
    for (int o = 1; o < 16; o <<= 1) {
#pragma unroll
        for (int reg = 0; reg < 4; reg++) {
            ps[reg] += __shfl_xor(ps[reg], o, 64);
            pd[reg] += __shfl_xor(pd[reg], o, 64);
        }
    }
    if (r == 0) {
#pragma unroll
        for (int reg = 0; reg < 4; reg++) {
            sS[rowbase + reg] = ps[reg];
            sD[rowbase + reg] = pd[reg];
        }
    }
}

// ---------------- FC1: A fp32 (split in-kernel), W pre-split hi/lo ----------------

__launch_bounds__(256)
__global__ void gemm_fc1(const float* __restrict__ A,
                         const unsigned short* __restrict__ Whi,
                         const unsigned short* __restrict__ Wlo,
                         const float* __restrict__ bias,
                         const float* __restrict__ attn,
                         unsigned short* __restrict__ Zb,
                         float* __restrict__ sS, float* __restrict__ sD) {
    int wave = blockIdx.x * 4 + (threadIdx.x >> 6);
    if (wave >= GEMM_WAVES) return;
    int lane = threadIdx.x & 63;
    int m0 = wave * 16;
    int r  = lane & 15;
    int ko = (lane >> 4) * 8;

    const float* Ap = A + (size_t)(m0 + r) * IN_DIM + ko;
    const unsigned short* Wh = Whi + (size_t)r * IN_DIM + ko;
    const unsigned short* Wl = Wlo + (size_t)r * IN_DIM + ko;

    f32x4 acc[8];
#pragma unroll
    for (int i = 0; i < 8; i++) acc[i] = (f32x4){0.f, 0.f, 0.f, 0.f};

#pragma unroll
    for (int kt = 0; kt < IN_DIM / 32; kt++) {
        float4 f0 = *(const float4*)(Ap + kt * 32);
        float4 f1 = *(const float4*)(Ap + kt * 32 + 4);
        float xs[8] = {f0.x, f0.y, f0.z, f0.w, f1.x, f1.y, f1.z, f1.w};
        short8 ahi, alo;
#pragma unroll
        for (int j = 0; j < 8; j++) {
            unsigned short hbits = f2bf(xs[j]);
            ahi[j] = (short)hbits;
            alo[j] = (short)f2bf(xs[j] - bf2f(hbits));
        }
#pragma unroll
        for (int nt = 0; nt < 8; nt++) {
            short8 bhi = *(const short8*)(Wh + (size_t)nt * 16 * IN_DIM + kt * 32);
            short8 blo = *(const short8*)(Wl + (size_t)nt * 16 * IN_DIM + kt * 32);
            acc[nt] = __builtin_amdgcn_mfma_f32_16x16x32_bf16(ahi, bhi, acc[nt], 0, 0, 0);
            acc[nt] = __builtin_amdgcn_mfma_f32_16x16x32_bf16(alo, bhi, acc[nt], 0, 0, 0);
            acc[nt] = __builtin_amdgcn_mfma_f32_16x16x32_bf16(ahi, blo, acc[nt], 0, 0, 0);
        }
    }
    gemm_epilogue(acc, m0, lane, bias, attn, Zb, sS, sD);
}

// ---------------- FC2: A is h1 (single bf16 plane), W pre-split hi/lo ----------------

__launch_bounds__(256)
__global__ void gemm_fc2(const unsigned short* __restrict__ Abf,
                         const unsigned short* __restrict__ Whi,
                         const unsigned short* __restrict__ Wlo,
                         const float* __restrict__ bias,
                         const float* __restrict__ attn,
                         unsigned short* __restrict__ Zb,
                         float* __restrict__ sS, float* __restrict__ sD) {
    int wave = blockIdx.x * 4 + (threadIdx.x >> 6);
    if (wave >= GEMM_WAVES) return;
    int lane = threadIdx.x & 63;
    int m0 = wave * 16;
    int r  = lane & 15;
    int ko = (lane >> 4) * 8;

    const unsigned short* Ap = Abf + (size_t)(m0 + r) * HID + ko;
    const unsigned short* Wh = Whi + (size_t)r * HID + ko;
    const unsigned short* Wl = Wlo + (size_t)r * HID + ko;

    f32x4 acc[8];
#pragma unroll
    for (int i = 0; i < 8; i++) acc[i] = (f32x4){0.f, 0.f, 0.f, 0.f};

#pragma unroll
    for (int kt = 0; kt < HID / 32; kt++) {
        short8 af = *(const short8*)(Ap + kt * 32);
#pragma unroll
        for (int nt = 0; nt < 8; nt++) {
            short8 bhi = *(const short8*)(Wh + (size_t)nt * 16 * HID + kt * 32);
            short8 blo = *(const short8*)(Wl + (size_t)nt * 16 * HID + kt * 32);
            acc[nt] = __builtin_amdgcn_mfma_f32_16x16x32_bf16(af, bhi, acc[nt], 0, 0, 0);
            acc[nt] = __builtin_amdgcn_mfma_f32_16x16x32_bf16(af, blo, acc[nt], 0, 0, 0);
        }
    }
    gemm_epilogue(acc, m0, lane, bias, attn, Zb, sS, sD);
}

// ---------------- segment softmax + weighted gather-sum + ELU ----------------
// one wave per dst node; phase C unrolled x4 for memory-level parallelism.
// csr_src slot loads are wave-uniform (scalar); only the z-row gather is vector.

template <int OUT_BF>
__launch_bounds__(256)
__global__ void aggregate(const unsigned short* __restrict__ Zb,
                          const int* __restrict__ csr_src,
                          const int* __restrict__ offsets,
                          const float* __restrict__ sS,
                          const float* __restrict__ sD,
                          const float* __restrict__ ab,
                          unsigned short* __restrict__ OutBf,
                          float* __restrict__ OutF) {
    int v = blockIdx.x * 4 + (threadIdx.x >> 6);
    int lane = threadIdx.x & 63;
    int off = offsets[v];
    int deg = offsets[v + 1] - off;
    float sdv = sD[v] + ab[0];

    // phase A: segment max of leaky_relu(e)   (edge-parallel across lanes)
    float mx = -3.0e38f;
    for (int t = lane; t < deg; t += 64)
        mx = fmaxf(mx, lky(sS[csr_src[off + t]] + sdv));
#pragma unroll
    for (int o = 32; o > 0; o >>= 1) mx = fmaxf(mx, __shfl_xor(mx, o, 64));

    // phase B: softmax denom
    float sum = 0.f;
    for (int t = lane; t < deg; t += 64)
        sum += __expf(lky(sS[csr_src[off + t]] + sdv) - mx);
#pragma unroll
    for (int o = 32; o > 0; o >>= 1) sum += __shfl_xor(sum, o, 64);
    float inv = (deg > 0) ? 1.f / sum : 0.f;

    // phase C: weighted sum of z[src] rows; lane covers dims 2*lane, 2*lane+1
    const unsigned int* Zrow = (const unsigned int*)Zb;  // dword = 2 bf16 dims
    float2 acc = {0.f, 0.f};
    int t = 0;
    for (; t + 4 <= deg; t += 4) {
        int s0 = csr_src[off + t];
        int s1 = csr_src[off + t + 1];
        int s2 = csr_src[off + t + 2];
        int s3 = csr_src[off + t + 3];
        float x0 = sS[s0], x1 = sS[s1], x2 = sS[s2], x3 = sS[s3];
        unsigned int r0 = Zrow[(size_t)s0 * (HID / 2) + lane];
        unsigned int r1 = Zrow[(size_t)s1 * (HID / 2) + lane];
        unsigned int r2 = Zrow[(size_t)s2 * (HID / 2) + lane];
        unsigned int r3 = Zrow[(size_t)s3 * (HID / 2) + lane];
        float a0 = __expf(lky(x0 + sdv) - mx) * inv;
        float a1 = __expf(lky(x1 + sdv) - mx) * inv;
        float a2 = __expf(lky(x2 + sdv) - mx) * inv;
        float a3 = __expf(lky(x3 + sdv) - mx) * inv;
        float2 z0 = bfu2(r0), z1 = bfu2(r1), z2 = bfu2(r2), z3 = bfu2(r3);
        acc.x += a0 * z0.x + a1 * z1.x + a2 * z2.x + a3 * z3.x;
        acc.y += a0 * z0.y + a1 * z1.y + a2 * z2.y + a3 * z3.y;
    }
    for (; t < deg; t++) {
        int s = csr_src[off + t];
        float al = __expf(lky(sS[s] + sdv) - mx) * inv;
        float2 zz = bfu2(Zrow[(size_t)s * (HID / 2) + lane]);
        acc.x += al * zz.x;
        acc.y += al * zz.y;
    }

    // ELU
    acc.x = acc.x > 0.f ? acc.x : __expf(acc.x) - 1.f;
    acc.y = acc.y > 0.f ? acc.y : __expf(acc.y) - 1.f;

    if (OUT_BF) {
        ushort2 o2;
        o2.x = f2bf(acc.x);
        o2.y = f2bf(acc.y);
        *((ushort2*)(OutBf + (size_t)v * HID + lane * 2)) = o2;
    } else {
        float2 o2 = {acc.x, acc.y};
        *((float2*)(OutF + (size_t)v * HID + lane * 2)) = o2;
    }
}

// ---------------- launch ----------------

extern "C" void kernel_launch(void* const* d_in, const int* in_sizes, int n_in,
                              void* d_out, int out_size, void* d_ws, size_t ws_size,
                              hipStream_t stream) {
    const float* h   = (const float*)d_in[0];
    const int*   src = (const int*)d_in[1];
    const int*   dst = (const int*)d_in[2];
    const float* W1  = (const float*)d_in[3];
    const float* b1  = (const float*)d_in[4];
    const float* a1  = (const float*)d_in[5];
    const float* ab1 = (const float*)d_in[6];
    const float* W2  = (const float*)d_in[7];
    const float* b2  = (const float*)d_in[8];
    const float* a2  = (const float*)d_in[9];
    const float* ab2 = (const float*)d_in[10];
    float* out = (float*)d_out;

    // workspace carve-up (all segments 16B-aligned)
    unsigned short* zb = (unsigned short*)d_ws;                 // 50000*128 bf16 = 12.8 MB
    float* sS = (float*)(zb + (size_t)N_NODES * HID);           // 50000 f32
    float* sD = sS + N_NODES;                                   // 50000 f32
    unsigned short* h1   = (unsigned short*)(sD + N_NODES);     // 50000*128 bf16
    unsigned short* w1hi = h1 + (size_t)N_NODES * HID;          // 128*256
    unsigned short* w1lo = w1hi + HID * IN_DIM;
    unsigned short* w2hi = w1lo + HID * IN_DIM;                 // 128*128
    unsigned short* w2lo = w2hi + HID * HID;
    int* counts  = (int*)(w2lo + HID * HID);                    // 50000
    int* offsets = counts + N_NODES;                            // 50001 (+pad)
    int* cursor  = offsets + N_NODES + 16;                      // 50000
    int* bsums   = cursor + N_NODES;                            // 256
    int* boffs   = bsums + 256;                                 // 256
    int* csr_src = boffs + 256;                                 // 800000

    hipMemsetAsync(counts, 0, N_NODES * sizeof(int), stream);
    hipMemsetAsync(cursor, 0, N_NODES * sizeof(int), stream);

    // CSR by dst (shared by both layers)
    hist_kernel<<<EDGE_BLOCKS, 256, 0, stream>>>(dst, counts);
    scan_block<<<SCAN_BLOCKS, 256, 0, stream>>>(counts, offsets, bsums);
    scan_tops<<<1, 256, 0, stream>>>(bsums, boffs);
    scan_add<<<SCAN_BLOCKS, 256, 0, stream>>>(offsets, boffs);
    fill_kernel<<<EDGE_BLOCKS, 256, 0, stream>>>(dst, src, offsets, cursor, csr_src);

    // weight splits
    split_w<<<(HID * IN_DIM + 255) / 256, 256, 0, stream>>>(W1, w1hi, w1lo, HID * IN_DIM);
    split_w<<<(HID * HID + 255) / 256, 256, 0, stream>>>(W2, w2hi, w2lo, HID * HID);

    // layer 1
    gemm_fc1<<<GEMM_BLOCKS, 256, 0, stream>>>(h, w1hi, w1lo, b1, a1, zb, sS, sD);
    aggregate<1><<<NODE_WBLKS, 256, 0, stream>>>(zb, csr_src, offsets, sS, sD, ab1, h1, nullptr);

    // layer 2
    gemm_fc2<<<GEMM_BLOCKS, 256, 0, stream>>>(h1, w2hi, w2lo, b2, a2, zb, sS, sD);
    aggregate<0><<<NODE_WBLKS, 256, 0, stream>>>(zb, csr_src, offsets, sS, sD, ab2, nullptr, out);
}

// Round 4
// 361.549 us; speedup vs baseline: 1.6410x; 1.0870x over previous
//
#include <hip/hip_runtime.h>
#include <hip/hip_bf16.h>

#define N_NODES 50000
#define N_EDGES 800000
#define IN_DIM  256
#define HID     128
#define LEAKY   0.01f

#define EDGE_BLOCKS  ((N_EDGES + 255) / 256)      // 3125
#define NODE_WBLKS   (N_NODES / 4)                // 12500
#define SCAN_BLOCKS  ((N_NODES + 255) / 256)      // 196
#define GEMM_WAVES   (N_NODES / 16 * 2)           // 6250 (N-split 2)
#define GEMM_BLOCKS  ((GEMM_WAVES + 3) / 4)       // 1563

typedef __attribute__((ext_vector_type(8))) short short8;
typedef __attribute__((ext_vector_type(4))) float f32x4;

__device__ __forceinline__ unsigned short f2bf(float x) {
    union { __hip_bfloat16 b; unsigned short u; } c;
    c.b = __float2bfloat16(x);
    return c.u;
}
__device__ __forceinline__ float bf2f(unsigned short u) {
    union { unsigned int u; float f; } c;
    c.u = ((unsigned int)u) << 16;
    return c.f;
}
__device__ __forceinline__ float2 bfu2(unsigned int u) {
    float2 r;
    r.x = bf2f((unsigned short)(u & 0xffff));
    r.y = bf2f((unsigned short)(u >> 16));
    return r;
}
__device__ __forceinline__ float lky(float x) { return x > 0.f ? x : LEAKY * x; }

// ---------------- CSR build (dst identical for both layers) ----------------

__global__ void hist_kernel(const int* __restrict__ dst, int* __restrict__ counts) {
    int i = blockIdx.x * 256 + threadIdx.x;
    if (i < N_EDGES) atomicAdd(&counts[dst[i]], 1);
}

__global__ void scan_block(const int* __restrict__ counts, int* __restrict__ offsets,
                           int* __restrict__ bsums) {
    __shared__ int sh[256];
    int tid = threadIdx.x;
    int i = blockIdx.x * 256 + tid;
    int v = (i < N_NODES) ? counts[i] : 0;
    sh[tid] = v;
    __syncthreads();
    for (int o = 1; o < 256; o <<= 1) {
        int t = (tid >= o) ? sh[tid - o] : 0;
        __syncthreads();
        sh[tid] += t;
        __syncthreads();
    }
    if (i < N_NODES) offsets[i] = sh[tid] - v;
    if (tid == 255) bsums[blockIdx.x] = sh[255];
}

__global__ void scan_tops(const int* __restrict__ bsums, int* __restrict__ boffs) {
    __shared__ int sh[256];
    int tid = threadIdx.x;
    int v = (tid < SCAN_BLOCKS) ? bsums[tid] : 0;
    sh[tid] = v;
    __syncthreads();
    for (int o = 1; o < 256; o <<= 1) {
        int t = (tid >= o) ? sh[tid - o] : 0;
        __syncthreads();
        sh[tid] += t;
        __syncthreads();
    }
    if (tid < SCAN_BLOCKS) boffs[tid] = sh[tid] - v;
}

__global__ void scan_add(int* __restrict__ offsets, const int* __restrict__ boffs) {
    int i = blockIdx.x * 256 + threadIdx.x;
    if (i < N_NODES) offsets[i] += boffs[blockIdx.x];
    if (i == N_NODES) offsets[N_NODES] = N_EDGES;
}

__global__ void fill_kernel(const int* __restrict__ dst, const int* __restrict__ src,
                            const int* __restrict__ offsets,
                            int* __restrict__ cursor, int* __restrict__ csr_src) {
    int i = blockIdx.x * 256 + threadIdx.x;
    if (i < N_EDGES) {
        int d = dst[i];
        int p = atomicAdd(&cursor[d], 1);
        csr_src[offsets[d] + p] = src[i];
    }
}

// ---------------- both W splits in one dispatch ----------------

__global__ void split_w2(const float* __restrict__ Wa, unsigned short* __restrict__ ahi,
                         unsigned short* __restrict__ alo, int na,
                         const float* __restrict__ Wb, unsigned short* __restrict__ bhi,
                         unsigned short* __restrict__ blo, int nb) {
    int i = blockIdx.x * 256 + threadIdx.x;
    if (i < na) {
        float x = Wa[i];
        unsigned short h = f2bf(x);
        ahi[i] = h;
        alo[i] = f2bf(x - bf2f(h));
    } else if (i - na < nb) {
        int j = i - na;
        float x = Wb[j];
        unsigned short h = f2bf(x);
        bhi[j] = h;
        blo[j] = f2bf(x - bf2f(h));
    }
}

// ---------------- GEMM epilogue (N-split): bias + bf16 z + partial scores -------
// C/D layout: col = lane&15, row = (lane>>4)*4 + reg. Wave covers cols
// [q*64, q*64+64); shfl_xor over r reduces its partial dot; atomicAdd combines
// the two q-halves (sS/sD pre-zeroed).

__device__ __forceinline__ void gemm_epilogue(
        f32x4* acc, int m0, int q, int lane,
        const float* __restrict__ bias, const float* __restrict__ attn,
        unsigned short* __restrict__ Zb, float* __restrict__ sS, float* __restrict__ sD) {
    int r = lane & 15;
    int rowbase = m0 + (lane >> 4) * 4;
    float ps[4] = {0.f, 0.f, 0.f, 0.f};
    float pd[4] = {0.f, 0.f, 0.f, 0.f};
#pragma unroll
    for (int nt = 0; nt < 4; nt++) {
        int n = q * 64 + nt * 16 + r;
        float bn = bias[n];
        float aS = attn[n];
        float aD = attn[HID + n];
#pragma unroll
        for (int reg = 0; reg < 4; reg++) {
            float zv = acc[nt][reg] + bn;
            Zb[(size_t)(rowbase + reg) * HID + n] = f2bf(zv);
            ps[reg] += zv * aS;
            pd[reg] += zv * aD;
        }
    }
#pragma unroll
    for (int o = 1; o < 16; o <<= 1) {
#pragma unroll
        for (int reg = 0; reg < 4; reg++) {
            ps[reg] += __shfl_xor(ps[reg], o, 64);
            pd[reg] += __shfl_xor(pd[reg], o, 64);
        }
    }
    if (r == 0) {
#pragma unroll
        for (int reg = 0; reg < 4; reg++) {
            atomicAdd(&sS[rowbase + reg], ps[reg]);
            atomicAdd(&sD[rowbase + reg], pd[reg]);
        }
    }
}

// ---------------- FC1: A fp32 (split in-kernel + prefetch), W pre-split ----------

__launch_bounds__(256)
__global__ void gemm_fc1(const float* __restrict__ A,
                         const unsigned short* __restrict__ Whi,
                         const unsigned short* __restrict__ Wlo,
                         const float* __restrict__ bias,
                         const float* __restrict__ attn,
                         unsigned short* __restrict__ Zb,
                         float* __restrict__ sS, float* __restrict__ sD) {
    int wave = blockIdx.x * 4 + (threadIdx.x >> 6);
    if (wave >= GEMM_WAVES) return;
    int lane = threadIdx.x & 63;
    int m0 = (wave >> 1) * 16;
    int q  = wave & 1;
    int r  = lane & 15;
    int ko = (lane >> 4) * 8;

    const float* Ap = A + (size_t)(m0 + r) * IN_DIM + ko;
    const unsigned short* Wh = Whi + (size_t)(q * 64 + r) * IN_DIM + ko;
    const unsigned short* Wl = Wlo + (size_t)(q * 64 + r) * IN_DIM + ko;

    f32x4 acc[4];
#pragma unroll
    for (int i = 0; i < 4; i++) acc[i] = (f32x4){0.f, 0.f, 0.f, 0.f};

    float4 f0 = *(const float4*)(Ap);
    float4 f1 = *(const float4*)(Ap + 4);

#pragma unroll
    for (int kt = 0; kt < IN_DIM / 32; kt++) {
        float4 nf0, nf1;
        if (kt < IN_DIM / 32 - 1) {
            nf0 = *(const float4*)(Ap + (kt + 1) * 32);
            nf1 = *(const float4*)(Ap + (kt + 1) * 32 + 4);
        }
        float xs[8] = {f0.x, f0.y, f0.z, f0.w, f1.x, f1.y, f1.z, f1.w};
        short8 ahi, alo;
#pragma unroll
        for (int j = 0; j < 8; j++) {
            unsigned short hbits = f2bf(xs[j]);
            ahi[j] = (short)hbits;
            alo[j] = (short)f2bf(xs[j] - bf2f(hbits));
        }
#pragma unroll
        for (int nt = 0; nt < 4; nt++) {
            short8 bhi = *(const short8*)(Wh + (size_t)nt * 16 * IN_DIM + kt * 32);
            short8 blo = *(const short8*)(Wl + (size_t)nt * 16 * IN_DIM + kt * 32);
            acc[nt] = __builtin_amdgcn_mfma_f32_16x16x32_bf16(ahi, bhi, acc[nt], 0, 0, 0);
            acc[nt] = __builtin_amdgcn_mfma_f32_16x16x32_bf16(alo, bhi, acc[nt], 0, 0, 0);
            acc[nt] = __builtin_amdgcn_mfma_f32_16x16x32_bf16(ahi, blo, acc[nt], 0, 0, 0);
        }
        f0 = nf0;
        f1 = nf1;
    }
    gemm_epilogue(acc, m0, q, lane, bias, attn, Zb, sS, sD);
}

// ---------------- FC2: A bf16 (prefetch), W pre-split ----------------

__launch_bounds__(256)
__global__ void gemm_fc2(const unsigned short* __restrict__ Abf,
                         const unsigned short* __restrict__ Whi,
                         const unsigned short* __restrict__ Wlo,
                         const float* __restrict__ bias,
                         const float* __restrict__ attn,
                         unsigned short* __restrict__ Zb,
                         float* __restrict__ sS, float* __restrict__ sD) {
    int wave = blockIdx.x * 4 + (threadIdx.x >> 6);
    if (wave >= GEMM_WAVES) return;
    int lane = threadIdx.x & 63;
    int m0 = (wave >> 1) * 16;
    int q  = wave & 1;
    int r  = lane & 15;
    int ko = (lane >> 4) * 8;

    const unsigned short* Ap = Abf + (size_t)(m0 + r) * HID + ko;
    const unsigned short* Wh = Whi + (size_t)(q * 64 + r) * HID + ko;
    const unsigned short* Wl = Wlo + (size_t)(q * 64 + r) * HID + ko;

    f32x4 acc[4];
#pragma unroll
    for (int i = 0; i < 4; i++) acc[i] = (f32x4){0.f, 0.f, 0.f, 0.f};

    short8 af = *(const short8*)(Ap);

#pragma unroll
    for (int kt = 0; kt < HID / 32; kt++) {
        short8 naf;
        if (kt < HID / 32 - 1) naf = *(const short8*)(Ap + (kt + 1) * 32);
#pragma unroll
        for (int nt = 0; nt < 4; nt++) {
            short8 bhi = *(const short8*)(Wh + (size_t)nt * 16 * HID + kt * 32);
            short8 blo = *(const short8*)(Wl + (size_t)nt * 16 * HID + kt * 32);
            acc[nt] = __builtin_amdgcn_mfma_f32_16x16x32_bf16(af, bhi, acc[nt], 0, 0, 0);
            acc[nt] = __builtin_amdgcn_mfma_f32_16x16x32_bf16(af, blo, acc[nt], 0, 0, 0);
        }
        af = naf;
    }
    gemm_epilogue(acc, m0, q, lane, bias, attn, Zb, sS, sD);
}

// ---------------- segment softmax + weighted gather-sum + ELU ----------------
// one wave per dst node. Fast path (deg<=64): per-edge alpha computed once and
// held in lane registers; phase C broadcasts (src, alpha) via shfl — the only
// memory op in the serial loop is the z-row gather, unrolled x8.

template <int OUT_BF>
__launch_bounds__(256)
__global__ void aggregate(const unsigned short* __restrict__ Zb,
                          const int* __restrict__ csr_src,
                          const int* __restrict__ offsets,
                          const float* __restrict__ sS,
                          const float* __restrict__ sD,
                          const float* __restrict__ ab,
                          unsigned short* __restrict__ OutBf,
                          float* __restrict__ OutF) {
    int v = blockIdx.x * 4 + (threadIdx.x >> 6);
    int lane = threadIdx.x & 63;
    int off = offsets[v];
    int deg = offsets[v + 1] - off;
    float sdv = sD[v] + ab[0];

    const unsigned int* Zrow = (const unsigned int*)Zb;  // dword = 2 bf16 dims
    float2 acc = {0.f, 0.f};

    if (deg <= 64) {
        // ---- fast path ----
        bool act = lane < deg;
        int s_l = 0;
        float x = -3.0e38f;
        if (act) {
            s_l = csr_src[off + lane];
            x = lky(sS[s_l] + sdv);
        }
        float mx = x;
#pragma unroll
        for (int o = 32; o > 0; o >>= 1) mx = fmaxf(mx, __shfl_xor(mx, o, 64));
        float ex = act ? __expf(x - mx) : 0.f;
        float sum = ex;
#pragma unroll
        for (int o = 32; o > 0; o >>= 1) sum += __shfl_xor(sum, o, 64);
        float al_l = (deg > 0) ? ex / sum : 0.f;

        int t = 0;
        for (; t + 8 <= deg; t += 8) {
            int   s[8];
            float a[8];
            unsigned int rw[8];
#pragma unroll
            for (int j = 0; j < 8; j++) {
                s[j] = __shfl(s_l, t + j, 64);
                a[j] = __shfl(al_l, t + j, 64);
            }
#pragma unroll
            for (int j = 0; j < 8; j++)
                rw[j] = Zrow[(size_t)s[j] * (HID / 2) + lane];
#pragma unroll
            for (int j = 0; j < 8; j++) {
                float2 zz = bfu2(rw[j]);
                acc.x += a[j] * zz.x;
                acc.y += a[j] * zz.y;
            }
        }
        for (; t < deg; t++) {
            int sj = __shfl(s_l, t, 64);
            float aj = __shfl(al_l, t, 64);
            float2 zz = bfu2(Zrow[(size_t)sj * (HID / 2) + lane]);
            acc.x += aj * zz.x;
            acc.y += aj * zz.y;
        }
    } else {
        // ---- slow path (deg > 64; correctness only) ----
        float mx = -3.0e38f;
        for (int t = lane; t < deg; t += 64)
            mx = fmaxf(mx, lky(sS[csr_src[off + t]] + sdv));
#pragma unroll
        for (int o = 32; o > 0; o >>= 1) mx = fmaxf(mx, __shfl_xor(mx, o, 64));
        float sum = 0.f;
        for (int t = lane; t < deg; t += 64)
            sum += __expf(lky(sS[csr_src[off + t]] + sdv) - mx);
#pragma unroll
        for (int o = 32; o > 0; o >>= 1) sum += __shfl_xor(sum, o, 64);
        float inv = 1.f / sum;
        for (int t = 0; t < deg; t++) {
            int s = csr_src[off + t];
            float al = __expf(lky(sS[s] + sdv) - mx) * inv;
            float2 zz = bfu2(Zrow[(size_t)s * (HID / 2) + lane]);
            acc.x += al * zz.x;
            acc.y += al * zz.y;
        }
    }

    // ELU
    acc.x = acc.x > 0.f ? acc.x : __expf(acc.x) - 1.f;
    acc.y = acc.y > 0.f ? acc.y : __expf(acc.y) - 1.f;

    if (OUT_BF) {
        ushort2 o2;
        o2.x = f2bf(acc.x);
        o2.y = f2bf(acc.y);
        *((ushort2*)(OutBf + (size_t)v * HID + lane * 2)) = o2;
    } else {
        float2 o2 = {acc.x, acc.y};
        *((float2*)(OutF + (size_t)v * HID + lane * 2)) = o2;
    }
}

// ---------------- launch ----------------

extern "C" void kernel_launch(void* const* d_in, const int* in_sizes, int n_in,
                              void* d_out, int out_size, void* d_ws, size_t ws_size,
                              hipStream_t stream) {
    const float* h   = (const float*)d_in[0];
    const int*   src = (const int*)d_in[1];
    const int*   dst = (const int*)d_in[2];
    const float* W1  = (const float*)d_in[3];
    const float* b1  = (const float*)d_in[4];
    const float* a1  = (const float*)d_in[5];
    const float* ab1 = (const float*)d_in[6];
    const float* W2  = (const float*)d_in[7];
    const float* b2  = (const float*)d_in[8];
    const float* a2  = (const float*)d_in[9];
    const float* ab2 = (const float*)d_in[10];
    float* out = (float*)d_out;

    // workspace carve-up; sS,sD,counts,cursor contiguous for one memset
    unsigned short* zb = (unsigned short*)d_ws;                 // 50000*128 bf16
    float* sS = (float*)(zb + (size_t)N_NODES * HID);           // 50000 f32
    float* sD = sS + N_NODES;                                   // 50000 f32
    int* counts  = (int*)(sD + N_NODES);                        // 50000
    int* cursor  = counts + N_NODES;                            // 50000
    int* offsets = cursor + N_NODES;                            // 50001 (+pad)
    int* bsums   = offsets + N_NODES + 16;                      // 256
    int* boffs   = bsums + 256;                                 // 256
    unsigned short* h1   = (unsigned short*)(boffs + 256);      // 50000*128 bf16
    unsigned short* w1hi = h1 + (size_t)N_NODES * HID;          // 128*256
    unsigned short* w1lo = w1hi + HID * IN_DIM;
    unsigned short* w2hi = w1lo + HID * IN_DIM;                 // 128*128
    unsigned short* w2lo = w2hi + HID * HID;
    int* csr_src = (int*)(w2lo + HID * HID);                    // 800000

    // zero sS, sD, counts, cursor in one shot (contiguous)
    hipMemsetAsync(sS, 0, 4 * (size_t)N_NODES * sizeof(int), stream);

    // CSR by dst (shared by both layers)
    hist_kernel<<<EDGE_BLOCKS, 256, 0, stream>>>(dst, counts);
    scan_block<<<SCAN_BLOCKS, 256, 0, stream>>>(counts, offsets, bsums);
    scan_tops<<<1, 256, 0, stream>>>(bsums, boffs);
    scan_add<<<SCAN_BLOCKS, 256, 0, stream>>>(offsets, boffs);
    fill_kernel<<<EDGE_BLOCKS, 256, 0, stream>>>(dst, src, offsets, cursor, csr_src);

    // weight splits (both in one dispatch)
    split_w2<<<(HID * IN_DIM + HID * HID + 255) / 256, 256, 0, stream>>>(
        W1, w1hi, w1lo, HID * IN_DIM, W2, w2hi, w2lo, HID * HID);

    // layer 1
    gemm_fc1<<<GEMM_BLOCKS, 256, 0, stream>>>(h, w1hi, w1lo, b1, a1, zb, sS, sD);
    aggregate<1><<<NODE_WBLKS, 256, 0, stream>>>(zb, csr_src, offsets, sS, sD, ab1, h1, nullptr);

    // re-zero sS/sD for layer 2's atomic accumulation
    hipMemsetAsync(sS, 0, 2 * (size_t)N_NODES * sizeof(float), stream);

    // layer 2
    gemm_fc2<<<GEMM_BLOCKS, 256, 0, stream>>>(h1, w2hi, w2lo, b2, a2, zb, sS, sD);
    aggregate<0><<<NODE_WBLKS, 256, 0, stream>>>(zb, csr_src, offsets, sS, sD, ab2, nullptr, out);
}

// Round 5
// 329.185 us; speedup vs baseline: 1.8023x; 1.0983x over previous
//
#include <hip/hip_runtime.h>
#include <hip/hip_bf16.h>

#define N_NODES 50000
#define N_EDGES 800000
#define IN_DIM  256
#define HID     128
#define LEAKY   0.01f

#define EDGE_BLOCKS  ((N_EDGES + 255) / 256)      // 3125
#define NODE_WBLKS   (N_NODES / 4)                // 12500
#define SCAN_BLOCKS  ((N_NODES + 255) / 256)      // 196
#define MTILES       ((N_NODES + 31) / 32)        // 1563 (32-row m-tiles)
#define GEMM_WAVES   (MTILES * 2)                 // 3126 (N-split 2)
#define GEMM_BLOCKS  ((GEMM_WAVES + 3) / 4)       // 782

typedef __attribute__((ext_vector_type(8))) short short8;
typedef __attribute__((ext_vector_type(4))) float f32x4;

__device__ __forceinline__ unsigned short f2bf(float x) {
    union { __hip_bfloat16 b; unsigned short u; } c;
    c.b = __float2bfloat16(x);
    return c.u;
}
__device__ __forceinline__ float bf2f(unsigned short u) {
    union { unsigned int u; float f; } c;
    c.u = ((unsigned int)u) << 16;
    return c.f;
}
__device__ __forceinline__ float2 bfu2(unsigned int u) {
    float2 r;
    r.x = bf2f((unsigned short)(u & 0xffff));
    r.y = bf2f((unsigned short)(u >> 16));
    return r;
}
__device__ __forceinline__ float lky(float x) { return x > 0.f ? x : LEAKY * x; }

// ---------------- CSR hist + W splits (fused, independent work) ----------------

__global__ void hist_split(const int* __restrict__ dst, int* __restrict__ counts,
                           const float* __restrict__ W1, unsigned short* __restrict__ w1hi,
                           unsigned short* __restrict__ w1lo,
                           const float* __restrict__ W2, unsigned short* __restrict__ w2hi,
                           unsigned short* __restrict__ w2lo) {
    int i = blockIdx.x * 256 + threadIdx.x;
    if (i < N_EDGES) atomicAdd(&counts[dst[i]], 1);
    if (i < HID * IN_DIM) {
        float x = W1[i];
        unsigned short h = f2bf(x);
        w1hi[i] = h;
        w1lo[i] = f2bf(x - bf2f(h));
    } else if (i < HID * IN_DIM + HID * HID) {
        int j = i - HID * IN_DIM;
        float x = W2[j];
        unsigned short h = f2bf(x);
        w2hi[j] = h;
        w2lo[j] = f2bf(x - bf2f(h));
    }
}

__global__ void scan_block(const int* __restrict__ counts, int* __restrict__ offsets,
                           int* __restrict__ bsums) {
    __shared__ int sh[256];
    int tid = threadIdx.x;
    int i = blockIdx.x * 256 + tid;
    int v = (i < N_NODES) ? counts[i] : 0;
    sh[tid] = v;
    __syncthreads();
    for (int o = 1; o < 256; o <<= 1) {
        int t = (tid >= o) ? sh[tid - o] : 0;
        __syncthreads();
        sh[tid] += t;
        __syncthreads();
    }
    if (i < N_NODES) offsets[i] = sh[tid] - v;
    if (tid == 255) bsums[blockIdx.x] = sh[255];
}

// fused: each block reduces its bsums prefix, then adds (removes scan_tops kernel)
__global__ void scan_add(int* __restrict__ offsets, const int* __restrict__ bsums) {
    __shared__ int sh[256];
    int tid = threadIdx.x;
    int b = blockIdx.x;
    sh[tid] = (tid < b) ? bsums[tid] : 0;   // b <= 195 < 256
    __syncthreads();
    for (int o = 128; o > 0; o >>= 1) {
        if (tid < o) sh[tid] += sh[tid + o];
        __syncthreads();
    }
    int base = sh[0];
    int i = b * 256 + tid;
    if (i < N_NODES) offsets[i] += base;
    if (i == N_NODES) offsets[N_NODES] = N_EDGES;
}

__global__ void fill_kernel(const int* __restrict__ dst, const int* __restrict__ src,
                            const int* __restrict__ offsets,
                            int* __restrict__ cursor, int* __restrict__ csr_src) {
    int i = blockIdx.x * 256 + threadIdx.x;
    if (i < N_EDGES) {
        int d = dst[i];
        int p = atomicAdd(&cursor[d], 1);
        csr_src[offsets[d] + p] = src[i];
    }
}

// ---------------- GEMM epilogue for one 16-row subtile ----------------
// C/D: col = lane&15, row = (lane>>4)*4 + reg. Partial scores (64-col slice)
// reduce over r via shfl_xor, then PLAIN store to the q-plane (no atomics):
// sS[q*N + row], sD[q*N + row]. aggregate sums the two planes.

__device__ __forceinline__ void gemm_epilogue(
        const f32x4* acc, int m0, int q, int lane,
        const float* __restrict__ bias, const float* __restrict__ attn,
        unsigned short* __restrict__ Zb, float* __restrict__ sS, float* __restrict__ sD) {
    int r = lane & 15;
    int rowbase = m0 + (lane >> 4) * 4;
    float ps[4] = {0.f, 0.f, 0.f, 0.f};
    float pd[4] = {0.f, 0.f, 0.f, 0.f};
#pragma unroll
    for (int nt = 0; nt < 4; nt++) {
        int n = q * 64 + nt * 16 + r;
        float bn = bias[n];
        float aS = attn[n];
        float aD = attn[HID + n];
#pragma unroll
        for (int reg = 0; reg < 4; reg++) {
            float zv = acc[nt][reg] + bn;
            Zb[(size_t)(rowbase + reg) * HID + n] = f2bf(zv);
            ps[reg] += zv * aS;
            pd[reg] += zv * aD;
        }
    }
#pragma unroll
    for (int o = 1; o < 16; o <<= 1) {
#pragma unroll
        for (int reg = 0; reg < 4; reg++) {
            ps[reg] += __shfl_xor(ps[reg], o, 64);
            pd[reg] += __shfl_xor(pd[reg], o, 64);
        }
    }
    if (r == 0) {
#pragma unroll
        for (int reg = 0; reg < 4; reg++) {
            sS[q * N_NODES + rowbase + reg] = ps[reg];
            sD[q * N_NODES + rowbase + reg] = pd[reg];
        }
    }
}

// ---------------- FC1: 32 rows x 64 cols per wave; A fp32 split in-kernel -------

__launch_bounds__(256)
__global__ void gemm_fc1(const float* __restrict__ A,
                         const unsigned short* __restrict__ Whi,
                         const unsigned short* __restrict__ Wlo,
                         const float* __restrict__ bias,
                         const float* __restrict__ attn,
                         unsigned short* __restrict__ Zb,
                         float* __restrict__ sS, float* __restrict__ sD) {
    int wave = blockIdx.x * 4 + (threadIdx.x >> 6);
    if (wave >= GEMM_WAVES) return;
    int lane = threadIdx.x & 63;
    int mt = wave >> 1;
    int q  = wave & 1;
    int m0 = mt * 32;
    bool has2 = (m0 + 16 < N_NODES);   // tail tile (m0=49984) has only 16 rows
    int r  = lane & 15;
    int ko = (lane >> 4) * 8;

    const float* Ap0 = A + (size_t)(m0 + r) * IN_DIM + ko;
    const float* Ap1 = has2 ? (Ap0 + 16 * IN_DIM) : Ap0;
    const unsigned short* Wh = Whi + (size_t)(q * 64 + r) * IN_DIM + ko;
    const unsigned short* Wl = Wlo + (size_t)(q * 64 + r) * IN_DIM + ko;

    f32x4 acc0[4], acc1[4];
#pragma unroll
    for (int i = 0; i < 4; i++) {
        acc0[i] = (f32x4){0.f, 0.f, 0.f, 0.f};
        acc1[i] = (f32x4){0.f, 0.f, 0.f, 0.f};
    }

    float4 c00 = *(const float4*)(Ap0);
    float4 c01 = *(const float4*)(Ap0 + 4);
    float4 c10 = *(const float4*)(Ap1);
    float4 c11 = *(const float4*)(Ap1 + 4);

#pragma unroll
    for (int kt = 0; kt < IN_DIM / 32; kt++) {
        float4 n00, n01, n10, n11;
        if (kt < IN_DIM / 32 - 1) {
            n00 = *(const float4*)(Ap0 + (kt + 1) * 32);
            n01 = *(const float4*)(Ap0 + (kt + 1) * 32 + 4);
            n10 = *(const float4*)(Ap1 + (kt + 1) * 32);
            n11 = *(const float4*)(Ap1 + (kt + 1) * 32 + 4);
        }
        float x0[8] = {c00.x, c00.y, c00.z, c00.w, c01.x, c01.y, c01.z, c01.w};
        float x1[8] = {c10.x, c10.y, c10.z, c10.w, c11.x, c11.y, c11.z, c11.w};
        short8 ahi0, alo0, ahi1, alo1;
#pragma unroll
        for (int j = 0; j < 8; j++) {
            unsigned short h0 = f2bf(x0[j]);
            ahi0[j] = (short)h0;
            alo0[j] = (short)f2bf(x0[j] - bf2f(h0));
            unsigned short h1 = f2bf(x1[j]);
            ahi1[j] = (short)h1;
            alo1[j] = (short)f2bf(x1[j] - bf2f(h1));
        }
#pragma unroll
        for (int nt = 0; nt < 4; nt++) {
            short8 bhi = *(const short8*)(Wh + (size_t)nt * 16 * IN_DIM + kt * 32);
            short8 blo = *(const short8*)(Wl + (size_t)nt * 16 * IN_DIM + kt * 32);
            acc0[nt] = __builtin_amdgcn_mfma_f32_16x16x32_bf16(ahi0, bhi, acc0[nt], 0, 0, 0);
            acc0[nt] = __builtin_amdgcn_mfma_f32_16x16x32_bf16(alo0, bhi, acc0[nt], 0, 0, 0);
            acc0[nt] = __builtin_amdgcn_mfma_f32_16x16x32_bf16(ahi0, blo, acc0[nt], 0, 0, 0);
            acc1[nt] = __builtin_amdgcn_mfma_f32_16x16x32_bf16(ahi1, bhi, acc1[nt], 0, 0, 0);
            acc1[nt] = __builtin_amdgcn_mfma_f32_16x16x32_bf16(alo1, bhi, acc1[nt], 0, 0, 0);
            acc1[nt] = __builtin_amdgcn_mfma_f32_16x16x32_bf16(ahi1, blo, acc1[nt], 0, 0, 0);
        }
        if (kt < IN_DIM / 32 - 1) { c00 = n00; c01 = n01; c10 = n10; c11 = n11; }
    }
    gemm_epilogue(acc0, m0, q, lane, bias, attn, Zb, sS, sD);
    if (has2) gemm_epilogue(acc1, m0 + 16, q, lane, bias, attn, Zb, sS, sD);
}

// ---------------- FC2: 32 rows x 64 cols per wave; A bf16 ----------------

__launch_bounds__(256)
__global__ void gemm_fc2(const unsigned short* __restrict__ Abf,
                         const unsigned short* __restrict__ Whi,
                         const unsigned short* __restrict__ Wlo,
                         const float* __restrict__ bias,
                         const float* __restrict__ attn,
                         unsigned short* __restrict__ Zb,
                         float* __restrict__ sS, float* __restrict__ sD) {
    int wave = blockIdx.x * 4 + (threadIdx.x >> 6);
    if (wave >= GEMM_WAVES) return;
    int lane = threadIdx.x & 63;
    int mt = wave >> 1;
    int q  = wave & 1;
    int m0 = mt * 32;
    bool has2 = (m0 + 16 < N_NODES);
    int r  = lane & 15;
    int ko = (lane >> 4) * 8;

    const unsigned short* Ap0 = Abf + (size_t)(m0 + r) * HID + ko;
    const unsigned short* Ap1 = has2 ? (Ap0 + 16 * HID) : Ap0;
    const unsigned short* Wh = Whi + (size_t)(q * 64 + r) * HID + ko;
    const unsigned short* Wl = Wlo + (size_t)(q * 64 + r) * HID + ko;

    f32x4 acc0[4], acc1[4];
#pragma unroll
    for (int i = 0; i < 4; i++) {
        acc0[i] = (f32x4){0.f, 0.f, 0.f, 0.f};
        acc1[i] = (f32x4){0.f, 0.f, 0.f, 0.f};
    }

    short8 a0 = *(const short8*)(Ap0);
    short8 a1 = *(const short8*)(Ap1);

#pragma unroll
    for (int kt = 0; kt < HID / 32; kt++) {
        short8 na0, na1;
        if (kt < HID / 32 - 1) {
            na0 = *(const short8*)(Ap0 + (kt + 1) * 32);
            na1 = *(const short8*)(Ap1 + (kt + 1) * 32);
        }
#pragma unroll
        for (int nt = 0; nt < 4; nt++) {
            short8 bhi = *(const short8*)(Wh + (size_t)nt * 16 * HID + kt * 32);
            short8 blo = *(const short8*)(Wl + (size_t)nt * 16 * HID + kt * 32);
            acc0[nt] = __builtin_amdgcn_mfma_f32_16x16x32_bf16(a0, bhi, acc0[nt], 0, 0, 0);
            acc0[nt] = __builtin_amdgcn_mfma_f32_16x16x32_bf16(a0, blo, acc0[nt], 0, 0, 0);
            acc1[nt] = __builtin_amdgcn_mfma_f32_16x16x32_bf16(a1, bhi, acc1[nt], 0, 0, 0);
            acc1[nt] = __builtin_amdgcn_mfma_f32_16x16x32_bf16(a1, blo, acc1[nt], 0, 0, 0);
        }
        if (kt < HID / 32 - 1) { a0 = na0; a1 = na1; }
    }
    gemm_epilogue(acc0, m0, q, lane, bias, attn, Zb, sS, sD);
    if (has2) gemm_epilogue(acc1, m0 + 16, q, lane, bias, attn, Zb, sS, sD);
}

// ---------------- segment softmax + weighted gather-sum + ELU ----------------
// one wave per dst node; scores are sum of the two q-planes sS[s] + sS[s+N].

template <int OUT_BF>
__launch_bounds__(256)
__global__ void aggregate(const unsigned short* __restrict__ Zb,
                          const int* __restrict__ csr_src,
                          const int* __restrict__ offsets,
                          const float* __restrict__ sS,
                          const float* __restrict__ sD,
                          const float* __restrict__ ab,
                          unsigned short* __restrict__ OutBf,
                          float* __restrict__ OutF) {
    int v = blockIdx.x * 4 + (threadIdx.x >> 6);
    int lane = threadIdx.x & 63;
    int off = offsets[v];
    int deg = offsets[v + 1] - off;
    float sdv = sD[v] + sD[v + N_NODES] + ab[0];

    const unsigned int* Zrow = (const unsigned int*)Zb;  // dword = 2 bf16 dims
    float2 acc = {0.f, 0.f};

    if (deg <= 64) {
        // ---- fast path: per-edge alpha in lane registers, shfl broadcast ----
        bool act = lane < deg;
        int s_l = 0;
        float x = -3.0e38f;
        if (act) {
            s_l = csr_src[off + lane];
            x = lky(sS[s_l] + sS[s_l + N_NODES] + sdv);
        }
        float mx = x;
#pragma unroll
        for (int o = 32; o > 0; o >>= 1) mx = fmaxf(mx, __shfl_xor(mx, o, 64));
        float ex = act ? __expf(x - mx) : 0.f;
        float sum = ex;
#pragma unroll
        for (int o = 32; o > 0; o >>= 1) sum += __shfl_xor(sum, o, 64);
        float al_l = (deg > 0) ? ex / sum : 0.f;

        int t = 0;
        for (; t + 8 <= deg; t += 8) {
            int   s[8];
            float a[8];
            unsigned int rw[8];
#pragma unroll
            for (int j = 0; j < 8; j++) {
                s[j] = __shfl(s_l, t + j, 64);
                a[j] = __shfl(al_l, t + j, 64);
            }
#pragma unroll
            for (int j = 0; j < 8; j++)
                rw[j] = Zrow[(size_t)s[j] * (HID / 2) + lane];
#pragma unroll
            for (int j = 0; j < 8; j++) {
                float2 zz = bfu2(rw[j]);
                acc.x += a[j] * zz.x;
                acc.y += a[j] * zz.y;
            }
        }
        for (; t < deg; t++) {
            int sj = __shfl(s_l, t, 64);
            float aj = __shfl(al_l, t, 64);
            float2 zz = bfu2(Zrow[(size_t)sj * (HID / 2) + lane]);
            acc.x += aj * zz.x;
            acc.y += aj * zz.y;
        }
    } else {
        // ---- slow path (deg > 64) ----
        float mx = -3.0e38f;
        for (int t = lane; t < deg; t += 64) {
            int s = csr_src[off + t];
            mx = fmaxf(mx, lky(sS[s] + sS[s + N_NODES] + sdv));
        }
#pragma unroll
        for (int o = 32; o > 0; o >>= 1) mx = fmaxf(mx, __shfl_xor(mx, o, 64));
        float sum = 0.f;
        for (int t = lane; t < deg; t += 64) {
            int s = csr_src[off + t];
            sum += __expf(lky(sS[s] + sS[s + N_NODES] + sdv) - mx);
        }
#pragma unroll
        for (int o = 32; o > 0; o >>= 1) sum += __shfl_xor(sum, o, 64);
        float inv = 1.f / sum;
        for (int t = 0; t < deg; t++) {
            int s = csr_src[off + t];
            float al = __expf(lky(sS[s] + sS[s + N_NODES] + sdv) - mx) * inv;
            float2 zz = bfu2(Zrow[(size_t)s * (HID / 2) + lane]);
            acc.x += al * zz.x;
            acc.y += al * zz.y;
        }
    }

    // ELU
    acc.x = acc.x > 0.f ? acc.x : __expf(acc.x) - 1.f;
    acc.y = acc.y > 0.f ? acc.y : __expf(acc.y) - 1.f;

    if (OUT_BF) {
        ushort2 o2;
        o2.x = f2bf(acc.x);
        o2.y = f2bf(acc.y);
        *((ushort2*)(OutBf + (size_t)v * HID + lane * 2)) = o2;
    } else {
        float2 o2 = {acc.x, acc.y};
        *((float2*)(OutF + (size_t)v * HID + lane * 2)) = o2;
    }
}

// ---------------- launch ----------------

extern "C" void kernel_launch(void* const* d_in, const int* in_sizes, int n_in,
                              void* d_out, int out_size, void* d_ws, size_t ws_size,
                              hipStream_t stream) {
    const float* h   = (const float*)d_in[0];
    const int*   src = (const int*)d_in[1];
    const int*   dst = (const int*)d_in[2];
    const float* W1  = (const float*)d_in[3];
    const float* b1  = (const float*)d_in[4];
    const float* a1  = (const float*)d_in[5];
    const float* ab1 = (const float*)d_in[6];
    const float* W2  = (const float*)d_in[7];
    const float* b2  = (const float*)d_in[8];
    const float* a2  = (const float*)d_in[9];
    const float* ab2 = (const float*)d_in[10];
    float* out = (float*)d_out;

    // workspace carve-up
    unsigned short* zb = (unsigned short*)d_ws;                 // 50000*128 bf16
    float* sS = (float*)(zb + (size_t)N_NODES * HID);           // 2*50000 f32 (q-planes)
    float* sD = sS + 2 * N_NODES;                               // 2*50000 f32
    int* counts  = (int*)(sD + 2 * N_NODES);                    // 50000
    int* cursor  = counts + N_NODES;                            // 50000 (contiguous w/ counts)
    int* offsets = cursor + N_NODES;                            // 50001 (+pad)
    int* bsums   = offsets + N_NODES + 16;                      // 256
    unsigned short* h1   = (unsigned short*)(bsums + 256);      // 50000*128 bf16
    unsigned short* w1hi = h1 + (size_t)N_NODES * HID;          // 128*256
    unsigned short* w1lo = w1hi + HID * IN_DIM;
    unsigned short* w2hi = w1lo + HID * IN_DIM;                 // 128*128
    unsigned short* w2lo = w2hi + HID * HID;
    int* csr_src = (int*)(w2lo + HID * HID);                    // 800000

    // zero counts + cursor (contiguous)
    hipMemsetAsync(counts, 0, 2 * (size_t)N_NODES * sizeof(int), stream);

    // CSR by dst + weight splits
    hist_split<<<EDGE_BLOCKS, 256, 0, stream>>>(dst, counts, W1, w1hi, w1lo, W2, w2hi, w2lo);
    scan_block<<<SCAN_BLOCKS, 256, 0, stream>>>(counts, offsets, bsums);
    scan_add<<<SCAN_BLOCKS, 256, 0, stream>>>(offsets, bsums);
    fill_kernel<<<EDGE_BLOCKS, 256, 0, stream>>>(dst, src, offsets, cursor, csr_src);

    // layer 1
    gemm_fc1<<<GEMM_BLOCKS, 256, 0, stream>>>(h, w1hi, w1lo, b1, a1, zb, sS, sD);
    aggregate<1><<<NODE_WBLKS, 256, 0, stream>>>(zb, csr_src, offsets, sS, sD, ab1, h1, nullptr);

    // layer 2
    gemm_fc2<<<GEMM_BLOCKS, 256, 0, stream>>>(h1, w2hi, w2lo, b2, a2, zb, sS, sD);
    aggregate<0><<<NODE_WBLKS, 256, 0, stream>>>(zb, csr_src, offsets, sS, sD, ab2, nullptr, out);
}